// Round 4
// baseline (99.101 us; speedup 1.0000x reference)
//
#include <hip/hip_runtime.h>
#include <math.h>

#define NPART 2048
#define MSE_THREADS 256
#define MSE_UNROLL 10
#define B 64
#define N 54
#define E 54
#define C 5
#define TOTAL_BLOCKS (NPART + B)
#define LOG_CLAMP (-100.0f)

// Single fused kernel:
//  blocks [0, NPART)        : MSE partial over pred_dist/ref_dist (batched loads)
//  blocks [NPART, NPART+B)  : per-batch argmin + CE + BCE
//  last block to finish     : final reduction -> out[0]
__global__ __launch_bounds__(MSE_THREADS) void k_main(const float* __restrict__ pred_dist,
                                                      const float* __restrict__ ref_dist,
                                                      const float* __restrict__ pred_nodes,
                                                      const float* __restrict__ pred_edges,
                                                      const float* __restrict__ ref_nodes,
                                                      const float* __restrict__ ref_edges,
                                                      const int* __restrict__ ref_term,
                                                      unsigned int* __restrict__ cnt,  // ws[0], memset to 0 per call
                                                      float* __restrict__ part,        // [NPART]
                                                      float* __restrict__ nll,         // [B]
                                                      float* __restrict__ out,         // [0]=loss,[1..B]=min_inds
                                                      int n4, float inv_total) {
    const int t = threadIdx.x;

    if (blockIdx.x < NPART) {
        // ---- MSE streaming path ----
        const float4* __restrict__ p4 = (const float4*)pred_dist;
        const float4* __restrict__ r4 = (const float4*)ref_dist;
        const int stride = NPART * MSE_THREADS;
        int idx = blockIdx.x * MSE_THREADS + t;
        float acc = 0.0f;

        if (n4 == stride * MSE_UNROLL) {
            // fast path: issue all 20 loads, then fence the scheduler so the
            // FMAs cannot be hoisted between them -> ~20 loads in flight/thread
            float4 a[MSE_UNROLL], b[MSE_UNROLL];
            #pragma unroll
            for (int u = 0; u < MSE_UNROLL; u++) a[u] = p4[idx + u * stride];
            #pragma unroll
            for (int u = 0; u < MSE_UNROLL; u++) b[u] = r4[idx + u * stride];
            __builtin_amdgcn_sched_barrier(0);
            #pragma unroll
            for (int u = 0; u < MSE_UNROLL; u++) {
                float d0 = a[u].x - b[u].x, d1 = a[u].y - b[u].y;
                float d2 = a[u].z - b[u].z, d3 = a[u].w - b[u].w;
                acc = fmaf(d0, d0, acc);
                acc = fmaf(d1, d1, acc);
                acc = fmaf(d2, d2, acc);
                acc = fmaf(d3, d3, acc);
            }
        } else {
            for (int i = idx; i < n4; i += stride) {
                float4 a = p4[i];
                float4 b = r4[i];
                float d0 = a.x - b.x, d1 = a.y - b.y, d2 = a.z - b.z, d3 = a.w - b.w;
                acc = fmaf(d0, d0, acc);
                acc = fmaf(d1, d1, acc);
                acc = fmaf(d2, d2, acc);
                acc = fmaf(d3, d3, acc);
            }
        }

        #pragma unroll
        for (int off = 32; off > 0; off >>= 1) acc += __shfl_down(acc, off, 64);
        __shared__ float s[MSE_THREADS / 64];
        int lane = t & 63;
        int w = t >> 6;
        if (lane == 0) s[w] = acc;
        __syncthreads();
        if (t == 0) {
            float v = 0.0f;
            #pragma unroll
            for (int i = 0; i < MSE_THREADS / 64; i++) v += s[i];
            part[blockIdx.x] = v;
        }
    } else if (t < 64) {
        // ---- per-batch path: one wave does batch b ----
        int b = blockIdx.x - NPART;
        const float* pn = pred_nodes + b * (3 + C);
        float px = pn[0], py = pn[1], pz = pn[2];

        float d2 = 1e30f;
        int mi = t;
        if (t < N) {
            const float* rn = ref_nodes + ((long)b * N + t) * 4;
            float dx = rn[0] - px, dy = rn[1] - py, dz = rn[2] - pz;
            d2 = dx * dx + dy * dy + dz * dz;
        }
        #pragma unroll
        for (int off = 32; off > 0; off >>= 1) {
            float od = __shfl_down(d2, off, 64);
            int oi = __shfl_down(mi, off, 64);
            if (od < d2 || (od == d2 && oi < mi)) { d2 = od; mi = oi; }
        }
        mi = __shfl(mi, 0, 64); // broadcast argmin (first-index tie-break)

        int tgt = (int)ref_nodes[((long)b * N + mi) * 4 + 3];
        const float* logits = pn + 3;
        float m = logits[0];
        #pragma unroll
        for (int c = 1; c < C; c++) m = fmaxf(m, logits[c]);
        float se = 0.0f;
        #pragma unroll
        for (int c = 0; c < C; c++) se += __expf(logits[c] - m);
        float ce = logf(se) + m - logits[tgt];

        float term = 0.0f;
        if (t < E) {
            float sel = ref_edges[((long)b * N + mi) * E + t];
            float p = pred_edges[b * E + t];
            float lp = fmaxf(logf(p), LOG_CLAMP);
            float l1mp = fmaxf(log1pf(-p), LOG_CLAMP);
            term = -(sel * lp + (1.0f - sel) * l1mp);
        }
        #pragma unroll
        for (int off = 32; off > 0; off >>= 1) term += __shfl_down(term, off, 64);

        if (t == 0) {
            float active = (ref_term[b] == 0) ? 1.0f : 0.0f;
            float ne = active * (term / (float)E);
            if (isnan(ne)) ne = 0.0f;
            nll[b] = active * ce + ne;
            out[1 + b] = (float)mi;
        }
    }

    // ---- last-block-done finalize ----
    __shared__ int s_last;
    if (t == 0) {
        __threadfence();                              // release: part/nll visible
        unsigned int old = atomicAdd(cnt, 1u);
        s_last = (old == (unsigned int)(TOTAL_BLOCKS - 1)) ? 1 : 0;
    }
    __syncthreads();
    if (s_last) {
        __threadfence();                              // acquire: invalidate stale L2
        const float4* part4 = (const float4*)part;
        float acc = 0.0f;
        #pragma unroll
        for (int r = 0; r < NPART / 4 / MSE_THREADS; r++) {
            float4 v = part4[t + r * MSE_THREADS];
            acc += (v.x + v.y) + (v.z + v.w);
        }
        float nacc = (t < B) ? nll[t] : 0.0f;
        #pragma unroll
        for (int off = 32; off > 0; off >>= 1) {
            acc += __shfl_down(acc, off, 64);
            nacc += __shfl_down(nacc, off, 64);
        }
        __shared__ float s_p[4], s_n[4];
        int lane = t & 63;
        int w = t >> 6;
        if (lane == 0) { s_p[w] = acc; s_n[w] = nacc; }
        __syncthreads();
        if (t == 0) {
            float mse = (s_p[0] + s_p[1] + s_p[2] + s_p[3]) * inv_total;
            float ns = s_n[0] + s_n[1] + s_n[2] + s_n[3];
            out[0] = mse + ns * (1.0f / (float)B);
        }
    }
}

extern "C" void kernel_launch(void* const* d_in, const int* in_sizes, int n_in,
                              void* d_out, int out_size, void* d_ws, size_t ws_size,
                              hipStream_t stream) {
    const float* pred_nodes = (const float*)d_in[0];
    const float* pred_edges = (const float*)d_in[1];
    const float* pred_dist  = (const float*)d_in[2];
    const float* ref_nodes  = (const float*)d_in[3];
    const float* ref_edges  = (const float*)d_in[4];
    const int*   ref_term   = (const int*)d_in[5];
    const float* ref_dist   = (const float*)d_in[6];

    float* out = (float*)d_out;                 // [0]=loss, [1..64]=min_inds (as float)
    unsigned int* cnt = (unsigned int*)d_ws;    // [0]: completion counter
    float* part = (float*)d_ws + 4;             // 16B-aligned, NPART partials
    float* nll  = part + NPART;                 // B combined per-batch losses

    int n_dist = in_sizes[2];                   // 64*20*128*128 = 20971520
    int n4 = n_dist / 4;

    hipMemsetAsync(d_ws, 0, 4, stream);
    k_main<<<TOTAL_BLOCKS, MSE_THREADS, 0, stream>>>(pred_dist, ref_dist, pred_nodes,
                                                     pred_edges, ref_nodes, ref_edges,
                                                     ref_term, cnt, part, nll, out,
                                                     n4, 1.0f / (float)n_dist);
}

// Round 5
// 78.163 us; speedup vs baseline: 1.2679x; 1.2679x over previous
//
#include <hip/hip_runtime.h>
#include <math.h>

#define NPART 2048
#define MSE_THREADS 256
#define MSE_UNROLL 10
#define B 64
#define N 54
#define E 54
#define C 5
#define TOTAL_BLOCKS (NPART + B)
#define LOG_CLAMP (-100.0f)
#define MSE_SCALE 262144.0          // 2^18 fixed point for sum of squares
#define NLL_SCALE 4294967296.0      // 2^32 fixed point for per-batch losses

// Single fused kernel, no fences:
//  blocks [0, B)            : per-batch argmin + CE + BCE  -> u64 atomic acc[1]
//  blocks [B, B+NPART)      : MSE partial                   -> u64 atomic acc[0]
//  last block (counter)     : convert accumulators, write out[0]
// Integer atomics are order-independent => bit-deterministic across replays.
__global__ __launch_bounds__(MSE_THREADS) void k_main(const float* __restrict__ pred_dist,
                                                      const float* __restrict__ ref_dist,
                                                      const float* __restrict__ pred_nodes,
                                                      const float* __restrict__ pred_edges,
                                                      const float* __restrict__ ref_nodes,
                                                      const float* __restrict__ ref_edges,
                                                      const int* __restrict__ ref_term,
                                                      unsigned long long* __restrict__ acc, // [0]=mse,[1]=nll (zeroed per call)
                                                      unsigned int* __restrict__ cnt,       // zeroed per call
                                                      float* __restrict__ out,              // [0]=loss,[1..B]=min_inds
                                                      int n4, float inv_total) {
    const int t = threadIdx.x;

    if (blockIdx.x >= B) {
        // ---- MSE streaming path ----
        const float4* __restrict__ p4 = (const float4*)pred_dist;
        const float4* __restrict__ r4 = (const float4*)ref_dist;
        const int stride = NPART * MSE_THREADS;
        int idx = (blockIdx.x - B) * MSE_THREADS + t;
        float facc = 0.0f;
        for (int i = idx; i < n4; i += stride) {
            float4 a = p4[i];
            float4 b = r4[i];
            float d0 = a.x - b.x, d1 = a.y - b.y, d2 = a.z - b.z, d3 = a.w - b.w;
            facc = fmaf(d0, d0, facc);
            facc = fmaf(d1, d1, facc);
            facc = fmaf(d2, d2, facc);
            facc = fmaf(d3, d3, facc);
        }

        #pragma unroll
        for (int off = 32; off > 0; off >>= 1) facc += __shfl_down(facc, off, 64);
        __shared__ float s[MSE_THREADS / 64];
        int lane = t & 63;
        int w = t >> 6;
        if (lane == 0) s[w] = facc;
        __syncthreads();
        if (t == 0) {
            float v = 0.0f;
            #pragma unroll
            for (int i = 0; i < MSE_THREADS / 64; i++) v += s[i];
            // v >= 0 always; fixed-point, order-independent accumulation
            unsigned long long q = (unsigned long long)((double)v * MSE_SCALE + 0.5);
            atomicAdd(&acc[0], q);
        }
    } else if (t < 64) {
        // ---- per-batch path: one wave does batch b ----
        int b = blockIdx.x;
        const float* pn = pred_nodes + b * (3 + C);
        float px = pn[0], py = pn[1], pz = pn[2];

        float d2 = 1e30f;
        int mi = t;
        if (t < N) {
            const float* rn = ref_nodes + ((long)b * N + t) * 4;
            float dx = rn[0] - px, dy = rn[1] - py, dz = rn[2] - pz;
            d2 = dx * dx + dy * dy + dz * dz;
        }
        #pragma unroll
        for (int off = 32; off > 0; off >>= 1) {
            float od = __shfl_down(d2, off, 64);
            int oi = __shfl_down(mi, off, 64);
            if (od < d2 || (od == d2 && oi < mi)) { d2 = od; mi = oi; }
        }
        mi = __shfl(mi, 0, 64); // broadcast argmin (first-index tie-break)

        int tgt = (int)ref_nodes[((long)b * N + mi) * 4 + 3];
        const float* logits = pn + 3;
        float m = logits[0];
        #pragma unroll
        for (int c = 1; c < C; c++) m = fmaxf(m, logits[c]);
        float se = 0.0f;
        #pragma unroll
        for (int c = 0; c < C; c++) se += __expf(logits[c] - m);
        float ce = logf(se) + m - logits[tgt];

        float term = 0.0f;
        if (t < E) {
            float sel = ref_edges[((long)b * N + mi) * E + t];
            float p = pred_edges[b * E + t];
            float lp = fmaxf(logf(p), LOG_CLAMP);
            float l1mp = fmaxf(log1pf(-p), LOG_CLAMP);
            term = -(sel * lp + (1.0f - sel) * l1mp);
        }
        #pragma unroll
        for (int off = 32; off > 0; off >>= 1) term += __shfl_down(term, off, 64);

        if (t == 0) {
            float active = (ref_term[b] == 0) ? 1.0f : 0.0f;
            float ne = active * (term / (float)E);
            if (isnan(ne)) ne = 0.0f;
            float nl = active * ce + ne;   // >= 0 always
            out[1 + b] = (float)mi;
            unsigned long long q = (unsigned long long)((double)nl * NLL_SCALE + 0.5);
            atomicAdd(&acc[1], q);
        }
    }

    // ---- last-block-done finalize (atomics only, no fences) ----
    if (t == 0) {
        // ensure this block's data atomic has completed (acked at coherent
        // point) before the counter increment becomes visible
        asm volatile("s_waitcnt vmcnt(0)" ::: "memory");
        unsigned int old = atomicAdd(cnt, 1u);
        if (old == (unsigned int)(TOTAL_BLOCKS - 1)) {
            // coherent reads of the accumulators via atomic RMW with 0
            unsigned long long ms = atomicAdd(&acc[0], 0ull);
            unsigned long long ns = atomicAdd(&acc[1], 0ull);
            double mse = (double)ms * (1.0 / MSE_SCALE) * (double)inv_total;
            double nll = (double)ns * (1.0 / NLL_SCALE) * (1.0 / (double)B);
            out[0] = (float)(mse + nll);
        }
    }
}

extern "C" void kernel_launch(void* const* d_in, const int* in_sizes, int n_in,
                              void* d_out, int out_size, void* d_ws, size_t ws_size,
                              hipStream_t stream) {
    const float* pred_nodes = (const float*)d_in[0];
    const float* pred_edges = (const float*)d_in[1];
    const float* pred_dist  = (const float*)d_in[2];
    const float* ref_nodes  = (const float*)d_in[3];
    const float* ref_edges  = (const float*)d_in[4];
    const int*   ref_term   = (const int*)d_in[5];
    const float* ref_dist   = (const float*)d_in[6];

    float* out = (float*)d_out;                       // [0]=loss, [1..64]=min_inds
    unsigned long long* acc = (unsigned long long*)d_ws;  // [0]=mse, [1]=nll
    unsigned int* cnt = (unsigned int*)(acc + 2);

    int n_dist = in_sizes[2];                         // 64*20*128*128 = 20971520
    int n4 = n_dist / 4;

    hipMemsetAsync(d_ws, 0, 24, stream);
    k_main<<<TOTAL_BLOCKS, MSE_THREADS, 0, stream>>>(pred_dist, ref_dist, pred_nodes,
                                                     pred_edges, ref_nodes, ref_edges,
                                                     ref_term, acc, cnt, out,
                                                     n4, 1.0f / (float)n_dist);
}

// Round 6
// 34.351 us; speedup vs baseline: 2.8849x; 2.2754x over previous
//
#include <hip/hip_runtime.h>
#include <math.h>

#define NPART 1984                    // MSE blocks; + B batch blocks = 2048 = 8*256 CUs
#define MSE_THREADS 256
#define B 64
#define N 54
#define E 54
#define C 5
#define LOG_CLAMP (-100.0f)

// ---------------- Kernel 1: fused per-batch losses + MSE partials ----------------
// Blocks [0, B)        : per-batch argmin + CE + BCE (one wave active) -- run first
// Blocks [B, B+NPART)  : grid-strided MSE partial over pred/ref dist
// No atomics, no fences: cross-block data goes through regular stores; the
// second (tiny) kernel reduces. Total grid = 2048 = exact multiple of 256 CUs.
__global__ __launch_bounds__(MSE_THREADS) void k_main(const float* __restrict__ pred_dist,
                                                      const float* __restrict__ ref_dist,
                                                      const float* __restrict__ pred_nodes,
                                                      const float* __restrict__ pred_edges,
                                                      const float* __restrict__ ref_nodes,
                                                      const float* __restrict__ ref_edges,
                                                      const int* __restrict__ ref_term,
                                                      float* __restrict__ part,   // [NPART]
                                                      float* __restrict__ nll,    // [B]
                                                      float* __restrict__ out,    // [0]=loss,[1..B]=min_inds
                                                      int n4) {
    const int t = threadIdx.x;

    if (blockIdx.x >= B) {
        // ---- MSE streaming path ----
        const float4* __restrict__ p4 = (const float4*)pred_dist;
        const float4* __restrict__ r4 = (const float4*)ref_dist;
        const int stride = NPART * MSE_THREADS;
        int idx = (blockIdx.x - B) * MSE_THREADS + t;
        float acc = 0.0f;
        for (int i = idx; i < n4; i += stride) {
            float4 a = p4[i];
            float4 b = r4[i];
            float d0 = a.x - b.x, d1 = a.y - b.y, d2 = a.z - b.z, d3 = a.w - b.w;
            acc = fmaf(d0, d0, acc);
            acc = fmaf(d1, d1, acc);
            acc = fmaf(d2, d2, acc);
            acc = fmaf(d3, d3, acc);
        }

        #pragma unroll
        for (int off = 32; off > 0; off >>= 1) acc += __shfl_down(acc, off, 64);
        __shared__ float s[MSE_THREADS / 64];
        int lane = t & 63;
        int w = t >> 6;
        if (lane == 0) s[w] = acc;
        __syncthreads();
        if (t == 0) {
            float v = 0.0f;
            #pragma unroll
            for (int i = 0; i < MSE_THREADS / 64; i++) v += s[i];
            part[blockIdx.x - B] = v;
        }
    } else if (t < 64) {
        // ---- per-batch path: one wave does batch b ----
        int b = blockIdx.x;
        const float* pn = pred_nodes + b * (3 + C);
        float px = pn[0], py = pn[1], pz = pn[2];

        float d2 = 1e30f;
        int mi = t;
        if (t < N) {
            const float* rn = ref_nodes + ((long)b * N + t) * 4;
            float dx = rn[0] - px, dy = rn[1] - py, dz = rn[2] - pz;
            d2 = dx * dx + dy * dy + dz * dz;
        }
        #pragma unroll
        for (int off = 32; off > 0; off >>= 1) {
            float od = __shfl_down(d2, off, 64);
            int oi = __shfl_down(mi, off, 64);
            if (od < d2 || (od == d2 && oi < mi)) { d2 = od; mi = oi; }
        }
        mi = __shfl(mi, 0, 64); // broadcast argmin (first-index tie-break)

        // class CE (wave-uniform, cheap)
        int tgt = (int)ref_nodes[((long)b * N + mi) * 4 + 3];
        const float* logits = pn + 3;
        float m = logits[0];
        #pragma unroll
        for (int c = 1; c < C; c++) m = fmaxf(m, logits[c]);
        float se = 0.0f;
        #pragma unroll
        for (int c = 0; c < C; c++) se += __expf(logits[c] - m);
        float ce = logf(se) + m - logits[tgt];

        // edge BCE: lane t handles edge t
        float term = 0.0f;
        if (t < E) {
            float sel = ref_edges[((long)b * N + mi) * E + t];
            float p = pred_edges[b * E + t];
            float lp = fmaxf(logf(p), LOG_CLAMP);
            float l1mp = fmaxf(log1pf(-p), LOG_CLAMP);
            term = -(sel * lp + (1.0f - sel) * l1mp);
        }
        #pragma unroll
        for (int off = 32; off > 0; off >>= 1) term += __shfl_down(term, off, 64);

        if (t == 0) {
            float active = (ref_term[b] == 0) ? 1.0f : 0.0f;
            float ne = active * (term / (float)E);
            if (isnan(ne)) ne = 0.0f;
            nll[b] = active * ce + ne;
            out[1 + b] = (float)mi;
        }
    }
}

// ---------------- Kernel 2: finalize ----------------
__global__ __launch_bounds__(256) void k_final(const float* __restrict__ part,
                                               const float* __restrict__ nll,
                                               float* __restrict__ out,
                                               float inv_total) {
    int t = threadIdx.x;
    int lane = t & 63;
    int w = t >> 6;
    float acc = 0.0f;
    for (int i = t; i < NPART; i += 256) acc += part[i];
    float nacc = (t < B) ? nll[t] : 0.0f;
    #pragma unroll
    for (int off = 32; off > 0; off >>= 1) {
        acc += __shfl_down(acc, off, 64);
        nacc += __shfl_down(nacc, off, 64);
    }
    __shared__ float s_p[4], s_n[4];
    if (lane == 0) { s_p[w] = acc; s_n[w] = nacc; }
    __syncthreads();
    if (t == 0) {
        float mse = (s_p[0] + s_p[1] + s_p[2] + s_p[3]) * inv_total;
        float ns = s_n[0] + s_n[1] + s_n[2] + s_n[3];
        out[0] = mse + ns * (1.0f / (float)B);
    }
}

extern "C" void kernel_launch(void* const* d_in, const int* in_sizes, int n_in,
                              void* d_out, int out_size, void* d_ws, size_t ws_size,
                              hipStream_t stream) {
    const float* pred_nodes = (const float*)d_in[0];
    const float* pred_edges = (const float*)d_in[1];
    const float* pred_dist  = (const float*)d_in[2];
    const float* ref_nodes  = (const float*)d_in[3];
    const float* ref_edges  = (const float*)d_in[4];
    const int*   ref_term   = (const int*)d_in[5];
    const float* ref_dist   = (const float*)d_in[6];

    float* out  = (float*)d_out;      // [0]=loss, [1..64]=min_inds (as float)
    float* part = (float*)d_ws;       // NPART partials
    float* nll  = part + NPART;       // B combined per-batch losses

    int n_dist = in_sizes[2];         // 64*20*128*128 = 20971520
    int n4 = n_dist / 4;

    k_main<<<NPART + B, MSE_THREADS, 0, stream>>>(pred_dist, ref_dist, pred_nodes,
                                                  pred_edges, ref_nodes, ref_edges,
                                                  ref_term, part, nll, out, n4);
    k_final<<<1, 256, 0, stream>>>(part, nll, out, 1.0f / (float)n_dist);
}

// Round 7
// 34.044 us; speedup vs baseline: 2.9109x; 1.0090x over previous
//
#include <hip/hip_runtime.h>
#include <math.h>

#define NPART 2048                   // = 8 * 256 CUs exactly; 10 trips/thread exactly
#define MSE_THREADS 256
#define MSE_UNROLL 10
#define B 64
#define N 54
#define E 54
#define C 5
#define LOG_CLAMP (-100.0f)

// ---------------- Kernel 1: MSE partials everywhere; batch losses on blocks 0-63 ----------------
// All 2048 blocks: exactly-10-trip grid-strided MSE partial (perfect balance).
// Blocks [0, B): wave 0 additionally runs batch-b argmin + CE + BCE afterward;
// the ~1 µs dependent-load chain hides under the other blocks still streaming.
__global__ __launch_bounds__(MSE_THREADS) void k_main(const float* __restrict__ pred_dist,
                                                      const float* __restrict__ ref_dist,
                                                      const float* __restrict__ pred_nodes,
                                                      const float* __restrict__ pred_edges,
                                                      const float* __restrict__ ref_nodes,
                                                      const float* __restrict__ ref_edges,
                                                      const int* __restrict__ ref_term,
                                                      float* __restrict__ part,   // [NPART]
                                                      float* __restrict__ nll,    // [B]
                                                      float* __restrict__ out,    // [0]=loss,[1..B]=min_inds
                                                      int n4) {
    const int t = threadIdx.x;
    const int stride = NPART * MSE_THREADS;

    // ---- MSE streaming (all blocks) ----
    {
        const float4* __restrict__ p4 = (const float4*)pred_dist;
        const float4* __restrict__ r4 = (const float4*)ref_dist;
        int idx = blockIdx.x * MSE_THREADS + t;
        float acc = 0.0f;

        if (n4 == stride * MSE_UNROLL) {
            #pragma unroll
            for (int u = 0; u < MSE_UNROLL; u++) {
                float4 a = p4[idx + u * stride];
                float4 b = r4[idx + u * stride];
                float d0 = a.x - b.x, d1 = a.y - b.y, d2 = a.z - b.z, d3 = a.w - b.w;
                acc = fmaf(d0, d0, acc);
                acc = fmaf(d1, d1, acc);
                acc = fmaf(d2, d2, acc);
                acc = fmaf(d3, d3, acc);
            }
        } else {
            for (int i = idx; i < n4; i += stride) {
                float4 a = p4[i];
                float4 b = r4[i];
                float d0 = a.x - b.x, d1 = a.y - b.y, d2 = a.z - b.z, d3 = a.w - b.w;
                acc = fmaf(d0, d0, acc);
                acc = fmaf(d1, d1, acc);
                acc = fmaf(d2, d2, acc);
                acc = fmaf(d3, d3, acc);
            }
        }

        #pragma unroll
        for (int off = 32; off > 0; off >>= 1) acc += __shfl_down(acc, off, 64);
        __shared__ float s[MSE_THREADS / 64];
        int lane = t & 63;
        int w = t >> 6;
        if (lane == 0) s[w] = acc;
        __syncthreads();
        if (t == 0) {
            float v = 0.0f;
            #pragma unroll
            for (int i = 0; i < MSE_THREADS / 64; i++) v += s[i];
            part[blockIdx.x] = v;
        }
    }

    // ---- per-batch path (blocks 0..B-1, wave 0 only) ----
    if (blockIdx.x < B && t < 64) {
        int b = blockIdx.x;
        const float* pn = pred_nodes + b * (3 + C);
        float px = pn[0], py = pn[1], pz = pn[2];

        float d2 = 1e30f;
        int mi = t;
        if (t < N) {
            float4 rn = *(const float4*)(ref_nodes + ((long)b * N + t) * 4);
            float dx = rn.x - px, dy = rn.y - py, dz = rn.z - pz;
            d2 = dx * dx + dy * dy + dz * dz;
        }
        #pragma unroll
        for (int off = 32; off > 0; off >>= 1) {
            float od = __shfl_down(d2, off, 64);
            int oi = __shfl_down(mi, off, 64);
            if (od < d2 || (od == d2 && oi < mi)) { d2 = od; mi = oi; }
        }
        mi = __shfl(mi, 0, 64); // broadcast argmin (first-index tie-break)

        // class CE (wave-uniform, cheap)
        int tgt = (int)ref_nodes[((long)b * N + mi) * 4 + 3];
        const float* logits = pn + 3;
        float m = logits[0];
        #pragma unroll
        for (int c = 1; c < C; c++) m = fmaxf(m, logits[c]);
        float se = 0.0f;
        #pragma unroll
        for (int c = 0; c < C; c++) se += __expf(logits[c] - m);
        float ce = logf(se) + m - logits[tgt];

        // edge BCE: lane t handles edge t
        float term = 0.0f;
        if (t < E) {
            float sel = ref_edges[((long)b * N + mi) * E + t];
            float p = pred_edges[b * E + t];
            float lp = fmaxf(logf(p), LOG_CLAMP);
            float l1mp = fmaxf(log1pf(-p), LOG_CLAMP);
            term = -(sel * lp + (1.0f - sel) * l1mp);
        }
        #pragma unroll
        for (int off = 32; off > 0; off >>= 1) term += __shfl_down(term, off, 64);

        if (t == 0) {
            float active = (ref_term[b] == 0) ? 1.0f : 0.0f;
            float ne = active * (term / (float)E);
            if (isnan(ne)) ne = 0.0f;
            nll[b] = active * ce + ne;
            out[1 + b] = (float)mi;
        }
    }
}

// ---------------- Kernel 2: finalize ----------------
__global__ __launch_bounds__(256) void k_final(const float* __restrict__ part,
                                               const float* __restrict__ nll,
                                               float* __restrict__ out,
                                               float inv_total) {
    int t = threadIdx.x;
    int lane = t & 63;
    int w = t >> 6;
    float acc = 0.0f;
    #pragma unroll
    for (int r = 0; r < NPART / 256; r++) acc += part[t + r * 256];
    float nacc = (t < B) ? nll[t] : 0.0f;
    #pragma unroll
    for (int off = 32; off > 0; off >>= 1) {
        acc += __shfl_down(acc, off, 64);
        nacc += __shfl_down(nacc, off, 64);
    }
    __shared__ float s_p[4], s_n[4];
    if (lane == 0) { s_p[w] = acc; s_n[w] = nacc; }
    __syncthreads();
    if (t == 0) {
        float mse = (s_p[0] + s_p[1] + s_p[2] + s_p[3]) * inv_total;
        float ns = s_n[0] + s_n[1] + s_n[2] + s_n[3];
        out[0] = mse + ns * (1.0f / (float)B);
    }
}

extern "C" void kernel_launch(void* const* d_in, const int* in_sizes, int n_in,
                              void* d_out, int out_size, void* d_ws, size_t ws_size,
                              hipStream_t stream) {
    const float* pred_nodes = (const float*)d_in[0];
    const float* pred_edges = (const float*)d_in[1];
    const float* pred_dist  = (const float*)d_in[2];
    const float* ref_nodes  = (const float*)d_in[3];
    const float* ref_edges  = (const float*)d_in[4];
    const int*   ref_term   = (const int*)d_in[5];
    const float* ref_dist   = (const float*)d_in[6];

    float* out  = (float*)d_out;      // [0]=loss, [1..64]=min_inds (as float)
    float* part = (float*)d_ws;       // NPART partials
    float* nll  = part + NPART;       // B combined per-batch losses

    int n_dist = in_sizes[2];         // 64*20*128*128 = 20971520
    int n4 = n_dist / 4;

    k_main<<<NPART, MSE_THREADS, 0, stream>>>(pred_dist, ref_dist, pred_nodes,
                                              pred_edges, ref_nodes, ref_edges,
                                              ref_term, part, nll, out, n4);
    k_final<<<1, 256, 0, stream>>>(part, nll, out, 1.0f / (float)n_dist);
}

// Round 8
// 30.572 us; speedup vs baseline: 3.2416x; 1.1136x over previous
//
#include <hip/hip_runtime.h>
#include <math.h>

#define NPART 512                    // 512 blocks x 1024 thr = 2 blocks/CU; 10 trips exactly
#define MSE_THREADS 1024
#define MSE_UNROLL 10
#define B 64
#define N 54
#define E 54
#define C 5
#define LOG_CLAMP (-100.0f)

// ---------------- Kernel 1: MSE partials everywhere; batch losses on blocks 0-63 ----------------
// All 512 blocks: exactly-10-trip grid-strided MSE partial (perfect balance:
// 512*1024*10 = 5,242,880 float4 = the full tensor). Blocks [0,B): wave 0
// additionally runs batch-b argmin + CE + BCE afterward; its ~1-2 us dependent
// load chain hides under the blocks still streaming.
__global__ __launch_bounds__(MSE_THREADS) void k_main(const float* __restrict__ pred_dist,
                                                      const float* __restrict__ ref_dist,
                                                      const float* __restrict__ pred_nodes,
                                                      const float* __restrict__ pred_edges,
                                                      const float* __restrict__ ref_nodes,
                                                      const float* __restrict__ ref_edges,
                                                      const int* __restrict__ ref_term,
                                                      float* __restrict__ part,   // [NPART]
                                                      float* __restrict__ nll,    // [B]
                                                      float* __restrict__ out,    // [0]=loss,[1..B]=min_inds
                                                      int n4) {
    const int t = threadIdx.x;
    const int stride = NPART * MSE_THREADS;

    // ---- MSE streaming (all blocks) ----
    {
        const float4* __restrict__ p4 = (const float4*)pred_dist;
        const float4* __restrict__ r4 = (const float4*)ref_dist;
        int idx = blockIdx.x * MSE_THREADS + t;
        float acc = 0.0f;

        if (n4 == stride * MSE_UNROLL) {
            #pragma unroll
            for (int u = 0; u < MSE_UNROLL; u++) {
                float4 a = p4[idx + u * stride];
                float4 b = r4[idx + u * stride];
                float d0 = a.x - b.x, d1 = a.y - b.y, d2 = a.z - b.z, d3 = a.w - b.w;
                acc = fmaf(d0, d0, acc);
                acc = fmaf(d1, d1, acc);
                acc = fmaf(d2, d2, acc);
                acc = fmaf(d3, d3, acc);
            }
        } else {
            for (int i = idx; i < n4; i += stride) {
                float4 a = p4[i];
                float4 b = r4[i];
                float d0 = a.x - b.x, d1 = a.y - b.y, d2 = a.z - b.z, d3 = a.w - b.w;
                acc = fmaf(d0, d0, acc);
                acc = fmaf(d1, d1, acc);
                acc = fmaf(d2, d2, acc);
                acc = fmaf(d3, d3, acc);
            }
        }

        #pragma unroll
        for (int off = 32; off > 0; off >>= 1) acc += __shfl_down(acc, off, 64);
        __shared__ float s[MSE_THREADS / 64];
        int lane = t & 63;
        int w = t >> 6;
        if (lane == 0) s[w] = acc;
        __syncthreads();
        if (t < 64) {
            float v = (t < MSE_THREADS / 64) ? s[t] : 0.0f;
            #pragma unroll
            for (int off = 8; off > 0; off >>= 1) v += __shfl_down(v, off, 64);
            if (t == 0) part[blockIdx.x] = v;
        }
    }

    // ---- per-batch path (blocks 0..B-1, wave 0 only) ----
    if (blockIdx.x < B && t < 64) {
        int b = blockIdx.x;
        const float* pn = pred_nodes + b * (3 + C);
        float px = pn[0], py = pn[1], pz = pn[2];

        float d2 = 1e30f;
        int mi = t;
        if (t < N) {
            float4 rn = *(const float4*)(ref_nodes + ((long)b * N + t) * 4);
            float dx = rn.x - px, dy = rn.y - py, dz = rn.z - pz;
            d2 = dx * dx + dy * dy + dz * dz;
        }
        #pragma unroll
        for (int off = 32; off > 0; off >>= 1) {
            float od = __shfl_down(d2, off, 64);
            int oi = __shfl_down(mi, off, 64);
            if (od < d2 || (od == d2 && oi < mi)) { d2 = od; mi = oi; }
        }
        mi = __shfl(mi, 0, 64); // broadcast argmin (first-index tie-break)

        // class CE (wave-uniform, cheap)
        int tgt = (int)ref_nodes[((long)b * N + mi) * 4 + 3];
        const float* logits = pn + 3;
        float m = logits[0];
        #pragma unroll
        for (int c = 1; c < C; c++) m = fmaxf(m, logits[c]);
        float se = 0.0f;
        #pragma unroll
        for (int c = 0; c < C; c++) se += __expf(logits[c] - m);
        float ce = logf(se) + m - logits[tgt];

        // edge BCE: lane t handles edge t
        float term = 0.0f;
        if (t < E) {
            float sel = ref_edges[((long)b * N + mi) * E + t];
            float p = pred_edges[b * E + t];
            float lp = fmaxf(logf(p), LOG_CLAMP);
            float l1mp = fmaxf(log1pf(-p), LOG_CLAMP);
            term = -(sel * lp + (1.0f - sel) * l1mp);
        }
        #pragma unroll
        for (int off = 32; off > 0; off >>= 1) term += __shfl_down(term, off, 64);

        if (t == 0) {
            float active = (ref_term[b] == 0) ? 1.0f : 0.0f;
            float ne = active * (term / (float)E);
            if (isnan(ne)) ne = 0.0f;
            nll[b] = active * ce + ne;
            out[1 + b] = (float)mi;
        }
    }
}

// ---------------- Kernel 2: finalize (512 + 64 values) ----------------
__global__ __launch_bounds__(256) void k_final(const float* __restrict__ part,
                                               const float* __restrict__ nll,
                                               float* __restrict__ out,
                                               float inv_total) {
    int t = threadIdx.x;
    int lane = t & 63;
    int w = t >> 6;
    float acc = 0.0f;
    #pragma unroll
    for (int r = 0; r < NPART / 256; r++) acc += part[t + r * 256];
    float nacc = (t < B) ? nll[t] : 0.0f;
    #pragma unroll
    for (int off = 32; off > 0; off >>= 1) {
        acc += __shfl_down(acc, off, 64);
        nacc += __shfl_down(nacc, off, 64);
    }
    __shared__ float s_p[4], s_n[4];
    if (lane == 0) { s_p[w] = acc; s_n[w] = nacc; }
    __syncthreads();
    if (t == 0) {
        float mse = (s_p[0] + s_p[1] + s_p[2] + s_p[3]) * inv_total;
        float ns = s_n[0] + s_n[1] + s_n[2] + s_n[3];
        out[0] = mse + ns * (1.0f / (float)B);
    }
}

extern "C" void kernel_launch(void* const* d_in, const int* in_sizes, int n_in,
                              void* d_out, int out_size, void* d_ws, size_t ws_size,
                              hipStream_t stream) {
    const float* pred_nodes = (const float*)d_in[0];
    const float* pred_edges = (const float*)d_in[1];
    const float* pred_dist  = (const float*)d_in[2];
    const float* ref_nodes  = (const float*)d_in[3];
    const float* ref_edges  = (const float*)d_in[4];
    const int*   ref_term   = (const int*)d_in[5];
    const float* ref_dist   = (const float*)d_in[6];

    float* out  = (float*)d_out;      // [0]=loss, [1..64]=min_inds (as float)
    float* part = (float*)d_ws;       // NPART partials
    float* nll  = part + NPART;       // B combined per-batch losses

    int n_dist = in_sizes[2];         // 64*20*128*128 = 20971520
    int n4 = n_dist / 4;

    k_main<<<NPART, MSE_THREADS, 0, stream>>>(pred_dist, ref_dist, pred_nodes,
                                              pred_edges, ref_nodes, ref_edges,
                                              ref_term, part, nll, out, n4);
    k_final<<<1, 256, 0, stream>>>(part, nll, out, 1.0f / (float)n_dist);
}